// Round 3
// baseline (95.794 us; speedup 1.0000x reference)
//
#include <hip/hip_runtime.h>
#include <math.h>

#define BB 2
#define PP 4096
#define HH 128
#define WW 128
#define KK 8
#define TS 8             // tile size in pixels (8x8 = 64 pixels, 1 lane/pixel)
#define NTX (WW / TS)    // 16
#define NTY (HH / TS)    // 16
#define NW 8             // waves per block
#define SEG (PP / NW)    // 512 points per wave segment
#define CIT (SEG / 64)   // 8 cull iterations per wave
#define CAP 384          // max candidates per segment (mean ~17, 60-sigma safe)

// One block = one 8x8 pixel tile, 8 waves split the point range.
// Phase 1: each wave projects+culls its 512-point segment into its LDS slab
//          (ballot compaction, no atomics), all 24 global loads prefetched.
// Phase 2: each wave builds a per-pixel sorted top-8 over its candidates.
// Phase 3: lists published to LDS; wave 0 does an 8-way lexicographic
//          (z, idx) merge per pixel — reproduces jax.lax.top_k tie-break.
__global__ __launch_bounds__(64 * NW, 4) void raster_kernel(
    const float* __restrict__ pw,     // [B,P,3]
    const float* __restrict__ Rm,     // [B,3,3]
    const float* __restrict__ Tv,     // [B,3]
    const float* __restrict__ fo,     // [B]
    float* __restrict__ out,          // idx | zbuf | dists planes, each N floats
    int N)
{
    __shared__ union {
        float4 cand[NW][CAP];                                   // 49152 B
        struct { float z[NW][KK][64], i[NW][KK][64], d[NW][KK][64]; } mg; // 49152 B
    } sh;

    const int tx = blockIdx.x, ty = blockIdx.y, b = blockIdx.z;
    const int wv   = threadIdx.x >> 6;
    const int lane = threadIdx.x & 63;

    // ---- uniform camera params ----
    const float* r = Rm + b * 9;
    const float r00=r[0], r01=r[1], r02=r[2];
    const float r10=r[3], r11=r[4], r12=r[5];
    const float r20=r[6], r21=r[7], r22=r[8];
    const float t0=Tv[b*3+0], t1=Tv[b*3+1], t2=Tv[b*3+2];
    const float f = fo[b];

    const float R2f   = (float)(0.05 * 0.05);
    const float apron = 0.05f + 1e-5f;  // conservative; exact d2<R^2 test inside

    float gx_hi = 1.0f - 2.0f * ((float)(tx * TS)          + 0.5f) / (float)WW;
    float gx_lo = 1.0f - 2.0f * ((float)(tx * TS + TS - 1) + 0.5f) / (float)WW;
    float gy_hi = 1.0f - 2.0f * ((float)(ty * TS)          + 0.5f) / (float)HH;
    float gy_lo = 1.0f - 2.0f * ((float)(ty * TS + TS - 1) + 0.5f) / (float)HH;
    const float xmin = gx_lo - apron, xmax = gx_hi + apron;
    const float ymin = gy_lo - apron, ymax = gy_hi + apron;

    // ---- phase 1a: prefetch whole segment (24 loads in flight at once) ----
    float px[CIT], py[CIT], pz[CIT];
    const float* basep = pw + ((size_t)b * PP + wv * SEG + lane) * 3;
#pragma unroll
    for (int it = 0; it < CIT; ++it) {
        px[it] = basep[it * 192 + 0];   // 64 lanes * 3 floats = 192 per iter
        py[it] = basep[it * 192 + 1];
        pz[it] = basep[it * 192 + 2];
    }

    // ---- phase 1b: project + cull + ballot-compact into LDS ----
    int cnt = 0;
#pragma unroll
    for (int it = 0; it < CIT; ++it) {
        int i = wv * SEG + it * 64 + lane;
        float x = px[it], y = py[it], z = pz[it];
        // einsum order, rn ops to block FMA contraction (match numpy exactly)
        float vx = __fadd_rn(__fadd_rn(__fadd_rn(__fmul_rn(x, r00), __fmul_rn(y, r10)), __fmul_rn(z, r20)), t0);
        float vy = __fadd_rn(__fadd_rn(__fadd_rn(__fmul_rn(x, r01), __fmul_rn(y, r11)), __fmul_rn(z, r21)), t1);
        float vz = __fadd_rn(__fadd_rn(__fadd_rn(__fmul_rn(x, r02), __fmul_rn(y, r12)), __fmul_rn(z, r22)), t2);
        float xn = __fmul_rn(f, vx) / vz;
        float yn = __fmul_rn(f, vy) / vz;
        bool keep = (vz > 0.0f) && (xn >= xmin) && (xn <= xmax)
                                && (yn >= ymin) && (yn <= ymax);
        unsigned long long m = __ballot(keep);
        if (keep) {
            int slot = cnt + __popcll(m & ((1ull << lane) - 1ull));
            if (slot < CAP) sh.cand[wv][slot] = make_float4(xn, yn, vz, __int_as_float(i));
        }
        cnt += __popcll(m);           // wave-uniform
    }
    if (cnt > CAP) cnt = CAP;         // statically unreachable; safety only
    // intra-wave LDS RAW: in-order per wave — no barrier needed

    // ---- phase 2: per-pixel top-K over this wave's candidates ----
    int w = tx * TS + (lane & (TS - 1));
    int h = ty * TS + (lane / TS);
    float gx = 1.0f - 2.0f * ((float)w + 0.5f) / (float)WW;
    float gy = 1.0f - 2.0f * ((float)h + 0.5f) / (float)HH;

    float zk[KK], dk[KK]; int ik[KK];
#pragma unroll
    for (int j = 0; j < KK; ++j) { zk[j] = INFINITY; dk[j] = -1.0f; ik[j] = -1; }

    for (int s = 0; s < cnt; ++s) {
        float4 q = sh.cand[wv][s];     // broadcast ds_read_b128
        float dx = __fsub_rn(gx, q.x);
        float dy = __fsub_rn(gy, q.y);
        float d2 = __fadd_rn(__fmul_rn(dx, dx), __fmul_rn(dy, dy));
        float z = q.z;                 // z > 0 guaranteed by cull
        if (d2 < R2f && z < zk[KK - 1]) {
            int i = __float_as_int(q.w);
            // ascending index + strict '<' displacement == top_k tie-break
#pragma unroll
            for (int j = KK - 1; j >= 1; --j) {
                if (z < zk[j]) {
                    if (z < zk[j - 1]) { zk[j] = zk[j-1]; ik[j] = ik[j-1]; dk[j] = dk[j-1]; }
                    else               { zk[j] = z;       ik[j] = i;       dk[j] = d2;      }
                }
            }
            if (z < zk[0]) { zk[0] = z; ik[0] = i; dk[0] = d2; }
        }
    }

    // ---- phase 3: publish sorted lists, 8-way merge in wave 0 ----
    __syncthreads();                  // all waves done reading cand (union reuse)
#pragma unroll
    for (int s = 0; s < KK; ++s) {
        sh.mg.z[wv][s][lane] = zk[s];
        sh.mg.i[wv][s][lane] = __int_as_float(ik[s]);
        sh.mg.d[wv][s][lane] = dk[s];
    }
    __syncthreads();

    if (wv == 0) {
        float hz[NW], hd[NW]; int hi_[NW], hp[NW];
#pragma unroll
        for (int wq = 0; wq < NW; ++wq) {
            hp[wq]  = 0;
            hz[wq]  = sh.mg.z[wq][0][lane];
            hi_[wq] = __float_as_int(sh.mg.i[wq][0][lane]);
            hd[wq]  = sh.mg.d[wq][0][lane];
        }
        float A[KK], Z[KK], D[KK];
#pragma unroll
        for (int o = 0; o < KK; ++o) {
            int bw = 0;
#pragma unroll
            for (int wq = 1; wq < NW; ++wq) {
                bool better = (hz[wq] < hz[bw]) ||
                              ((hz[wq] == hz[bw]) && (hi_[wq] < hi_[bw]));
                if (better) bw = wq;
            }
            float sz = hz[0], sd = hd[0]; int si = hi_[0];
#pragma unroll
            for (int wq = 1; wq < NW; ++wq) {
                if (bw == wq) { sz = hz[wq]; sd = hd[wq]; si = hi_[wq]; }
            }
            A[o] = (float)si;
            Z[o] = (si >= 0) ? sz : -1.0f;
            D[o] = sd;
#pragma unroll
            for (int wq = 0; wq < NW; ++wq) {
                if (bw == wq) {
                    int p = ++hp[wq];
                    if (p < KK) {
                        hz[wq]  = sh.mg.z[wq][p][lane];
                        hi_[wq] = __float_as_int(sh.mg.i[wq][p][lane]);
                        hd[wq]  = sh.mg.d[wq][p][lane];
                    } else {
                        hz[wq] = INFINITY; hi_[wq] = -1; hd[wq] = -1.0f;
                    }
                }
            }
        }
        int pix  = (b * HH + h) * WW + w;
        int base = pix * KK;           // 32B-aligned
        float4* oa = (float4*)(out + base);
        float4* oz = (float4*)(out + N + base);
        float4* od = (float4*)(out + 2 * N + base);
        oa[0] = ((float4*)A)[0]; oa[1] = ((float4*)A)[1];
        oz[0] = ((float4*)Z)[0]; oz[1] = ((float4*)Z)[1];
        od[0] = ((float4*)D)[0]; od[1] = ((float4*)D)[1];
    }
}

extern "C" void kernel_launch(void* const* d_in, const int* in_sizes, int n_in,
                              void* d_out, int out_size, void* d_ws, size_t ws_size,
                              hipStream_t stream) {
    const float* pw = (const float*)d_in[0];   // points_world [B,P,3]
    const float* Rm = (const float*)d_in[1];   // R [B,3,3]
    const float* Tv = (const float*)d_in[2];   // T [B,3]
    const float* fo = (const float*)d_in[3];   // focal [B]
    int N = out_size / 3;                      // B*H*W*K

    hipLaunchKernelGGL(raster_kernel, dim3(NTX, NTY, BB), dim3(64 * NW), 0, stream,
                       pw, Rm, Tv, fo, (float*)d_out, N);
}